// Round 1
// baseline (449.152 us; speedup 1.0000x reference)
//
#include <hip/hip_runtime.h>

constexpr int NTHR = 256;

typedef short  short8 __attribute__((ext_vector_type(8)));  // 8 bf16 (4 VGPRs)
typedef float  f32x4  __attribute__((ext_vector_type(4)));

// factor row offsets per level: L0:0  L1:1  L2:5  L3:21  L4:85  L5:341
// Zero-barrier design: each wave owns 2 batches and the whole tree for them.
// All LDS buffers are wave-private (one aliased pool); intra-wave LDS ordering
// is guaranteed by compiler-inserted lgkmcnt waits. No __syncthreads.
//
// R6: occupancy push. LDS 38.4KB -> 18.6KB via lifetime-aliased per-wave pool
//     (path x / leaf+x5 / sy share one region; x5 4->2 buffers w/ per-p child
//     recompute; lat4 split out). VGPR diet: accinit -> s_hb LDS reads,
//     sy_ofs -> 6 packed u32. Target: 8 blocks/CU (whole grid resident,
//     32 waves/CU) with VGPR <= 64 via launch_bounds(256,8).

__device__ __forceinline__ unsigned short f2bf(float f) {
    union { float f; unsigned u; } v; v.f = f;
    unsigned r = v.u + 0x7FFFu + ((v.u >> 16) & 1u);   // RNE
    return (unsigned short)(r >> 16);
}

// lat[b][r] = scale[fo][r] * dot64(f_in[fo][r], xin[b])   (b=0..1, r=0..15)
__device__ __forceinline__ void wlat(const float* __restrict__ f_in,
                                     const float* __restrict__ scale,
                                     int fo,
                                     const float (*xin)[64],   // wave-private LDS [2][64]
                                     float (*lat)[16],         // wave-private LDS [2][16]
                                     int lane)
{
    const int b = lane >> 5;          // 0..1
    const int r = (lane >> 1) & 15;   // 0..15
    const int h = lane & 1;           // half of dot
    const float4* fir = (const float4*)(f_in + (size_t)fo * 1024 + r * 64 + h * 32);
    const float4* xb  = (const float4*)(&xin[b][0] + h * 32);
    float p = 0.f;
#pragma unroll
    for (int i = 0; i < 8; ++i) {
        const float4 a = fir[i], c = xb[i];
        p += a.x * c.x + a.y * c.y + a.z * c.z + a.w * c.w;
    }
    p += __shfl_xor(p, 1);
    if (h == 0) lat[b][r] = p * scale[fo * 16 + r];
}

// xout[b][o] = xin[b][o] + sum_r lat[b][r] * fd[r][o]
__device__ __forceinline__ void wchild(const float* __restrict__ fd,
                                       const float (*xin)[64],
                                       const float (*lat)[16],
                                       float (*xout)[64],
                                       int lane)
{
    const int o = lane;
    float f[16];
#pragma unroll
    for (int r = 0; r < 16; ++r) f[r] = fd[r * 64 + o];
#pragma unroll
    for (int b = 0; b < 2; ++b) {
        float acc = xin[b][o];
#pragma unroll
        for (int r = 0; r < 16; ++r) acc += lat[b][r] * f[r];
        xout[b][o] = acc;
    }
}

// leaf rows n = b*8 + nbase (bf16, stride 72 shorts)
__device__ __forceinline__ void wchild_leaf(const float* __restrict__ fd,
                                            const float (*xin)[64],
                                            const float (*lat)[16],
                                            unsigned short* leaf,   // [16][72]
                                            int nbase,
                                            int lane)
{
    const int o = lane;
    float f[16];
#pragma unroll
    for (int r = 0; r < 16; ++r) f[r] = fd[r * 64 + o];
#pragma unroll
    for (int b = 0; b < 2; ++b) {
        float acc = xin[b][o];
#pragma unroll
        for (int r = 0; r < 16; ++r) acc += lat[b][r] * f[r];
        leaf[(b * 8 + nbase) * 72 + o] = f2bf(acc);
    }
}

// min-waves/EU = 8 -> VGPR cap 64 (needed: occupancy halves above 64 per m69)
__global__ __launch_bounds__(NTHR, 8)
void qtree_kernel(const float* __restrict__ x,      // [128][64]
                  const float* __restrict__ f_in,   // [1365][16][64]
                  const float* __restrict__ f_tl,
                  const float* __restrict__ f_tr,
                  const float* __restrict__ f_bl,
                  const float* __restrict__ f_br,
                  const float* __restrict__ scale,  // [1365][16]
                  const float* __restrict__ head_w, // [48][64]
                  const float* __restrict__ head_b, // [48]
                  float* __restrict__ out)          // [128][3][256][256]
{
    // Per-wave aliased pool, 1152 floats = 4608 B:
    //   [0..831]   region (lifetime-aliased):
    //              phase A: xa[2][64] @0, xb[2][64] @128   (tree path, dead after L3)
    //              phase B: leaf[16][72] shorts @0 (576 f) + x5[2*2][64] @576 (256 f)
    //              phase C: sy[768] @0                      (output staging)
    //   [832..1087]  x4[2*2][64]  (L3 children, live across both jx)
    //   [1088..1119] lat[2][16]
    //   [1120..1151] lat4[2][16]  (L4 latent, survives L5 wlat overwrites of lat)
    // Total LDS: 4*4608 + 192 (s_hb) = 18624 B -> 8 blocks/CU.
    __shared__ __align__(16) float s_pool[4][1152];
    __shared__ float s_hb[48];

    const int tid  = threadIdx.x;
    const int wv   = tid >> 6;     // wave = batch pair
    const int lane = tid & 63;
    const int n    = lane & 15;    // MFMA N index (leaf in tile)
    const int q    = lane >> 4;    // quad
    const int n3   = blockIdx.x;   // 0..63  level-3 node (y3*8+x3)
    const int bg   = blockIdx.y;   // 0..15  batch group of 8
    const int jy   = blockIdx.z;   // 0..1
    const int y3   = n3 >> 3, x3 = n3 & 7;

    const float* fdir[4] = { f_tl, f_tr, f_bl, f_br };

    float* P = s_pool[wv];
    float (*xa)[64]  = (float(*)[64])P;            // region phase A
    float (*xb)[64]  = (float(*)[64])(P + 128);
    unsigned short* leaf = (unsigned short*)P;     // region phase B [16][72]
    float (*x5)[64]  = (float(*)[64])(P + 576);    // region phase B, rows dx2*2+b
    float* sy        = P;                           // region phase C [768]
    float (*x4)[64]  = (float(*)[64])(P + 832);    // rows jx*2+b
    float (*lat)[16] = (float(*)[16])(P + 1088);
    float (*lat4)[16]= (float(*)[16])(P + 1120);

    // head bias -> LDS (each wave writes identical values: benign race,
    // own-wave write-then-read is ordered; no barrier needed)
    if (lane < 48) s_hb[lane] = head_b[lane];

    // ---- per-lane head state (reused by all 8 head tiles) ----
    short8 afrag[3][2];
#pragma unroll
    for (int mt = 0; mt < 3; ++mt)
#pragma unroll
        for (int kc = 0; kc < 2; ++kc) {
            const float* src = head_w + (mt * 16 + n) * 64 + kc * 32 + q * 8;
            short8 a;
#pragma unroll
            for (int j = 0; j < 8; ++j) a[j] = (short)f2bf(src[j]);
            afrag[mt][kc] = a;
        }

    // s_y scatter offsets: leaf n -> (b, dx2, c); o = mt*16 + q*4 + r
    // packed 2x16b per u32 to save VGPRs (offsets < 768)
    const int lb = n >> 3, ldx = (n >> 2) & 1, lc = n & 3;
    const int lcy = lc >> 1, lcx = lc & 1;
    const int sy_base = lb * 384 + lcy * 64 + ldx * 8 + lcx * 4;
    unsigned sy_pk[6];
#pragma unroll
    for (int i = 0; i < 6; ++i) {
        unsigned lohi[2];
#pragma unroll
        for (int j = 0; j < 2; ++j) {
            const int t = 2 * i + j;                      // t = mt*4 + r
            const int o = (t >> 2) * 16 + q * 4 + (t & 3);
            lohi[j] = (unsigned)(sy_base + (o % 3) * 128 + (o / 12) * 16 + ((o / 3) & 3));
        }
        sy_pk[i] = lohi[0] | (lohi[1] << 16);
    }

    // load this wave's 2 batches
#pragma unroll
    for (int b = 0; b < 2; ++b)
        xa[b][lane] = x[(size_t)(bg * 8 + wv * 2 + b) * 64 + lane];

    // ---- path L0 -> L1 -> L2 (single child each) ----
    {
        wlat(f_in, scale, 0, xa, lat, lane);
        const int d = ((y3 >> 2) << 1) | (x3 >> 2);
        wchild(fdir[d], xa, lat, xb, lane);
    }
    {
        const int fo = 1 + ((y3 >> 2) * 2 + (x3 >> 2));
        wlat(f_in, scale, fo, xb, lat, lane);
        const int d = (((y3 >> 1) & 1) << 1) | ((x3 >> 1) & 1);
        wchild(fdir[d] + (size_t)fo * 1024, xb, lat, xa, lane);
    }
    {
        const int fo = 5 + ((y3 >> 1) * 4 + (x3 >> 1));
        wlat(f_in, scale, fo, xa, lat, lane);
        const int d = ((y3 & 1) << 1) | (x3 & 1);
        wchild(fdir[d] + (size_t)fo * 1024, xa, lat, xb, lane);
    }
    // ---- L3: children for this jy-half -> x4 (outside aliased region) ----
    {
        const int fo = 21 + n3;
        wlat(f_in, scale, fo, xb, lat, lane);
#pragma unroll
        for (int jx = 0; jx < 2; ++jx)
            wchild(fdir[2 * jy + jx] + (size_t)fo * 1024, xb, lat, &x4[2 * jx], lane);
    }
    // path xa/xb dead from here; region reused for leaf/x5/sy

    // ---- two L4 subtrees ----
    for (int jx = 0; jx < 2; ++jx) {
        const int y4 = 2 * y3 + jy, x4c = 2 * x3 + jx;
        const int fo4 = 85 + y4 * 16 + x4c;
        wlat(f_in, scale, fo4, &x4[2 * jx], lat4, lane);   // L4 latent persists in lat4

        // ---- 2 head tiles per subtree: p halves; children recomputed per p ----
        for (int p = 0; p < 2; ++p) {
#pragma unroll
            for (int dx2 = 0; dx2 < 2; ++dx2)
                wchild(fdir[2 * p + dx2] + (size_t)fo4 * 1024, &x4[2 * jx], lat4,
                       &x5[2 * dx2], lane);
#pragma unroll
            for (int dx2 = 0; dx2 < 2; ++dx2) {
                const int fo5 = 341 + (2 * y4 + p) * 32 + (2 * x4c + dx2);
                wlat(f_in, scale, fo5, &x5[2 * dx2], lat, lane);
#pragma unroll
                for (int c = 0; c < 4; ++c)
                    wchild_leaf(fdir[c] + (size_t)fo5 * 1024, &x5[2 * dx2], lat,
                                leaf, dx2 * 4 + c, lane);
            }

            // MFMA head: 16 leaves x 48 outs, K=64; bias from s_hb (3 LDS b128)
            f32x4 acc[3];
#pragma unroll
            for (int mt = 0; mt < 3; ++mt)
                acc[mt] = *(const f32x4*)&s_hb[mt * 16 + q * 4];
#pragma unroll
            for (int kc = 0; kc < 2; ++kc) {
                const short8 bfrag = *(const short8*)&leaf[n * 72 + kc * 32 + q * 8];
#pragma unroll
                for (int mt = 0; mt < 3; ++mt)
                    acc[mt] = __builtin_amdgcn_mfma_f32_16x16x32_bf16(afrag[mt][kc], bfrag, acc[mt], 0, 0, 0);
            }

            // stage y: [b][ch][r2][16]  (sy aliases leaf/x5 -- both dead now)
#pragma unroll
            for (int mt = 0; mt < 3; ++mt)
#pragma unroll
                for (int r = 0; r < 4; ++r) {
                    const int t = mt * 4 + r;
                    const int ofs = (sy_pk[t >> 1] >> (16 * (t & 1))) & 0xffff;
                    sy[ofs] = acc[mt][r];
                }

            // full-line stores: rows of 16 px (64 B)
            const int base_row = (4 * y3 + 2 * jy + p) * 8;
            const int base_col = (4 * x3 + 2 * jx) * 8;
#pragma unroll
            for (int s = 0; s < 3; ++s) {
                const int i  = lane + 64 * s;      // 0..191 float4 chunks
                const int c4 = i & 3;
                const int r2 = (i >> 2) & 7;
                const int bc = i >> 5;             // b*3+ch, 0..5
                const float4 v = *(const float4*)&sy[(bc * 8 + r2) * 16 + c4 * 4];
                const size_t off = ((size_t)((bg * 8 + wv * 2 + bc / 3) * 3 + (bc % 3))) * 65536
                                 + (size_t)(base_row + r2) * 256 + base_col + c4 * 4;
                *(float4*)&out[off] = v;
            }
        } // p
    } // jx
}

extern "C" void kernel_launch(void* const* d_in, const int* in_sizes, int n_in,
                              void* d_out, int out_size, void* d_ws, size_t ws_size,
                              hipStream_t stream) {
    const float* x    = (const float*)d_in[0];
    const float* f_in = (const float*)d_in[1];
    const float* f_tl = (const float*)d_in[2];
    const float* f_tr = (const float*)d_in[3];
    const float* f_bl = (const float*)d_in[4];
    const float* f_br = (const float*)d_in[5];
    const float* sc   = (const float*)d_in[6];
    const float* hw   = (const float*)d_in[7];
    const float* hb   = (const float*)d_in[8];
    float* out = (float*)d_out;

    dim3 grid(64, 16, 2);
    qtree_kernel<<<grid, NTHR, 0, stream>>>(x, f_in, f_tl, f_tr, f_bl, f_br, sc, hw, hb, out);
}

// Round 2
// 421.851 us; speedup vs baseline: 1.0647x; 1.0647x over previous
//
#include <hip/hip_runtime.h>

constexpr int NTHR = 256;

typedef short  short8 __attribute__((ext_vector_type(8)));  // 8 bf16 (4 VGPRs)
typedef float  f32x4  __attribute__((ext_vector_type(4)));

// factor row offsets per level: L0:0  L1:1  L2:5  L3:21  L4:85  L5:341
// Zero-barrier design: each wave owns 2 batches and the whole tree for them.
// All LDS buffers are wave-private (one aliased pool); intra-wave LDS ordering
// is guaranteed by compiler-inserted lgkmcnt waits. No __syncthreads.
//
// R6: LDS 38.4KB -> 18.6KB lifetime-aliased pool + VGPR diet.
// R7: launch_bounds (256,8)->(256,6). R6's 8-wave cap forced VGPR=32 and
//     ~560MB of scratch spill traffic (FETCH 28.6->399MB, WRITE 108->385MB).
//     6 waves/EU caps VGPR at ~85 -- diet body fits spill-free, and LDS
//     (6 x 18.9KB = 114KB) no longer binds. Target 24 waves/CU (75%).

__device__ __forceinline__ unsigned short f2bf(float f) {
    union { float f; unsigned u; } v; v.f = f;
    unsigned r = v.u + 0x7FFFu + ((v.u >> 16) & 1u);   // RNE
    return (unsigned short)(r >> 16);
}

// lat[b][r] = scale[fo][r] * dot64(f_in[fo][r], xin[b])   (b=0..1, r=0..15)
__device__ __forceinline__ void wlat(const float* __restrict__ f_in,
                                     const float* __restrict__ scale,
                                     int fo,
                                     const float (*xin)[64],   // wave-private LDS [2][64]
                                     float (*lat)[16],         // wave-private LDS [2][16]
                                     int lane)
{
    const int b = lane >> 5;          // 0..1
    const int r = (lane >> 1) & 15;   // 0..15
    const int h = lane & 1;           // half of dot
    const float4* fir = (const float4*)(f_in + (size_t)fo * 1024 + r * 64 + h * 32);
    const float4* xb  = (const float4*)(&xin[b][0] + h * 32);
    float p = 0.f;
#pragma unroll
    for (int i = 0; i < 8; ++i) {
        const float4 a = fir[i], c = xb[i];
        p += a.x * c.x + a.y * c.y + a.z * c.z + a.w * c.w;
    }
    p += __shfl_xor(p, 1);
    if (h == 0) lat[b][r] = p * scale[fo * 16 + r];
}

// xout[b][o] = xin[b][o] + sum_r lat[b][r] * fd[r][o]
__device__ __forceinline__ void wchild(const float* __restrict__ fd,
                                       const float (*xin)[64],
                                       const float (*lat)[16],
                                       float (*xout)[64],
                                       int lane)
{
    const int o = lane;
    float f[16];
#pragma unroll
    for (int r = 0; r < 16; ++r) f[r] = fd[r * 64 + o];
#pragma unroll
    for (int b = 0; b < 2; ++b) {
        float acc = xin[b][o];
#pragma unroll
        for (int r = 0; r < 16; ++r) acc += lat[b][r] * f[r];
        xout[b][o] = acc;
    }
}

// leaf rows n = b*8 + nbase (bf16, stride 72 shorts)
__device__ __forceinline__ void wchild_leaf(const float* __restrict__ fd,
                                            const float (*xin)[64],
                                            const float (*lat)[16],
                                            unsigned short* leaf,   // [16][72]
                                            int nbase,
                                            int lane)
{
    const int o = lane;
    float f[16];
#pragma unroll
    for (int r = 0; r < 16; ++r) f[r] = fd[r * 64 + o];
#pragma unroll
    for (int b = 0; b < 2; ++b) {
        float acc = xin[b][o];
#pragma unroll
        for (int r = 0; r < 16; ++r) acc += lat[b][r] * f[r];
        leaf[(b * 8 + nbase) * 72 + o] = f2bf(acc);
    }
}

// min-waves/EU = 6 -> VGPR cap ~85 (8 forced 32 VGPR + scratch spills in R6)
__global__ __launch_bounds__(NTHR, 6)
void qtree_kernel(const float* __restrict__ x,      // [128][64]
                  const float* __restrict__ f_in,   // [1365][16][64]
                  const float* __restrict__ f_tl,
                  const float* __restrict__ f_tr,
                  const float* __restrict__ f_bl,
                  const float* __restrict__ f_br,
                  const float* __restrict__ scale,  // [1365][16]
                  const float* __restrict__ head_w, // [48][64]
                  const float* __restrict__ head_b, // [48]
                  float* __restrict__ out)          // [128][3][256][256]
{
    // Per-wave aliased pool, 1152 floats = 4608 B:
    //   [0..831]   region (lifetime-aliased):
    //              phase A: xa[2][64] @0, xb[2][64] @128   (tree path, dead after L3)
    //              phase B: leaf[16][72] shorts @0 (576 f) + x5[2*2][64] @576 (256 f)
    //              phase C: sy[768] @0                      (output staging)
    //   [832..1087]  x4[2*2][64]  (L3 children, live across both jx)
    //   [1088..1119] lat[2][16]
    //   [1120..1151] lat4[2][16]  (L4 latent, survives L5 wlat overwrites of lat)
    // Total LDS: 4*4608 + 192 (s_hb) = 18624 B -> 6 blocks/CU (VGPR-capped).
    __shared__ __align__(16) float s_pool[4][1152];
    __shared__ float s_hb[48];

    const int tid  = threadIdx.x;
    const int wv   = tid >> 6;     // wave = batch pair
    const int lane = tid & 63;
    const int n    = lane & 15;    // MFMA N index (leaf in tile)
    const int q    = lane >> 4;    // quad
    const int n3   = blockIdx.x;   // 0..63  level-3 node (y3*8+x3)
    const int bg   = blockIdx.y;   // 0..15  batch group of 8
    const int jy   = blockIdx.z;   // 0..1
    const int y3   = n3 >> 3, x3 = n3 & 7;

    const float* fdir[4] = { f_tl, f_tr, f_bl, f_br };

    float* P = s_pool[wv];
    float (*xa)[64]  = (float(*)[64])P;            // region phase A
    float (*xb)[64]  = (float(*)[64])(P + 128);
    unsigned short* leaf = (unsigned short*)P;     // region phase B [16][72]
    float (*x5)[64]  = (float(*)[64])(P + 576);    // region phase B, rows dx2*2+b
    float* sy        = P;                           // region phase C [768]
    float (*x4)[64]  = (float(*)[64])(P + 832);    // rows jx*2+b
    float (*lat)[16] = (float(*)[16])(P + 1088);
    float (*lat4)[16]= (float(*)[16])(P + 1120);

    // head bias -> LDS (each wave writes identical values: benign race,
    // own-wave write-then-read is ordered; no barrier needed)
    if (lane < 48) s_hb[lane] = head_b[lane];

    // ---- per-lane head state (reused by all 8 head tiles) ----
    short8 afrag[3][2];
#pragma unroll
    for (int mt = 0; mt < 3; ++mt)
#pragma unroll
        for (int kc = 0; kc < 2; ++kc) {
            const float* src = head_w + (mt * 16 + n) * 64 + kc * 32 + q * 8;
            short8 a;
#pragma unroll
            for (int j = 0; j < 8; ++j) a[j] = (short)f2bf(src[j]);
            afrag[mt][kc] = a;
        }

    // s_y scatter offsets: leaf n -> (b, dx2, c); o = mt*16 + q*4 + r
    // packed 2x16b per u32 to save VGPRs (offsets < 768)
    const int lb = n >> 3, ldx = (n >> 2) & 1, lc = n & 3;
    const int lcy = lc >> 1, lcx = lc & 1;
    const int sy_base = lb * 384 + lcy * 64 + ldx * 8 + lcx * 4;
    unsigned sy_pk[6];
#pragma unroll
    for (int i = 0; i < 6; ++i) {
        unsigned lohi[2];
#pragma unroll
        for (int j = 0; j < 2; ++j) {
            const int t = 2 * i + j;                      // t = mt*4 + r
            const int o = (t >> 2) * 16 + q * 4 + (t & 3);
            lohi[j] = (unsigned)(sy_base + (o % 3) * 128 + (o / 12) * 16 + ((o / 3) & 3));
        }
        sy_pk[i] = lohi[0] | (lohi[1] << 16);
    }

    // load this wave's 2 batches
#pragma unroll
    for (int b = 0; b < 2; ++b)
        xa[b][lane] = x[(size_t)(bg * 8 + wv * 2 + b) * 64 + lane];

    // ---- path L0 -> L1 -> L2 (single child each) ----
    {
        wlat(f_in, scale, 0, xa, lat, lane);
        const int d = ((y3 >> 2) << 1) | (x3 >> 2);
        wchild(fdir[d], xa, lat, xb, lane);
    }
    {
        const int fo = 1 + ((y3 >> 2) * 2 + (x3 >> 2));
        wlat(f_in, scale, fo, xb, lat, lane);
        const int d = (((y3 >> 1) & 1) << 1) | ((x3 >> 1) & 1);
        wchild(fdir[d] + (size_t)fo * 1024, xb, lat, xa, lane);
    }
    {
        const int fo = 5 + ((y3 >> 1) * 4 + (x3 >> 1));
        wlat(f_in, scale, fo, xa, lat, lane);
        const int d = ((y3 & 1) << 1) | (x3 & 1);
        wchild(fdir[d] + (size_t)fo * 1024, xa, lat, xb, lane);
    }
    // ---- L3: children for this jy-half -> x4 (outside aliased region) ----
    {
        const int fo = 21 + n3;
        wlat(f_in, scale, fo, xb, lat, lane);
#pragma unroll
        for (int jx = 0; jx < 2; ++jx)
            wchild(fdir[2 * jy + jx] + (size_t)fo * 1024, xb, lat, &x4[2 * jx], lane);
    }
    // path xa/xb dead from here; region reused for leaf/x5/sy

    // ---- two L4 subtrees ----
    for (int jx = 0; jx < 2; ++jx) {
        const int y4 = 2 * y3 + jy, x4c = 2 * x3 + jx;
        const int fo4 = 85 + y4 * 16 + x4c;
        wlat(f_in, scale, fo4, &x4[2 * jx], lat4, lane);   // L4 latent persists in lat4

        // ---- 2 head tiles per subtree: p halves; children recomputed per p ----
        for (int p = 0; p < 2; ++p) {
#pragma unroll
            for (int dx2 = 0; dx2 < 2; ++dx2)
                wchild(fdir[2 * p + dx2] + (size_t)fo4 * 1024, &x4[2 * jx], lat4,
                       &x5[2 * dx2], lane);
#pragma unroll
            for (int dx2 = 0; dx2 < 2; ++dx2) {
                const int fo5 = 341 + (2 * y4 + p) * 32 + (2 * x4c + dx2);
                wlat(f_in, scale, fo5, &x5[2 * dx2], lat, lane);
#pragma unroll
                for (int c = 0; c < 4; ++c)
                    wchild_leaf(fdir[c] + (size_t)fo5 * 1024, &x5[2 * dx2], lat,
                                leaf, dx2 * 4 + c, lane);
            }

            // MFMA head: 16 leaves x 48 outs, K=64; bias from s_hb (3 LDS b128)
            f32x4 acc[3];
#pragma unroll
            for (int mt = 0; mt < 3; ++mt)
                acc[mt] = *(const f32x4*)&s_hb[mt * 16 + q * 4];
#pragma unroll
            for (int kc = 0; kc < 2; ++kc) {
                const short8 bfrag = *(const short8*)&leaf[n * 72 + kc * 32 + q * 8];
#pragma unroll
                for (int mt = 0; mt < 3; ++mt)
                    acc[mt] = __builtin_amdgcn_mfma_f32_16x16x32_bf16(afrag[mt][kc], bfrag, acc[mt], 0, 0, 0);
            }

            // stage y: [b][ch][r2][16]  (sy aliases leaf/x5 -- both dead now)
#pragma unroll
            for (int mt = 0; mt < 3; ++mt)
#pragma unroll
                for (int r = 0; r < 4; ++r) {
                    const int t = mt * 4 + r;
                    const int ofs = (sy_pk[t >> 1] >> (16 * (t & 1))) & 0xffff;
                    sy[ofs] = acc[mt][r];
                }

            // full-line stores: rows of 16 px (64 B)
            const int base_row = (4 * y3 + 2 * jy + p) * 8;
            const int base_col = (4 * x3 + 2 * jx) * 8;
#pragma unroll
            for (int s = 0; s < 3; ++s) {
                const int i  = lane + 64 * s;      // 0..191 float4 chunks
                const int c4 = i & 3;
                const int r2 = (i >> 2) & 7;
                const int bc = i >> 5;             // b*3+ch, 0..5
                const float4 v = *(const float4*)&sy[(bc * 8 + r2) * 16 + c4 * 4];
                const size_t off = ((size_t)((bg * 8 + wv * 2 + bc / 3) * 3 + (bc % 3))) * 65536
                                 + (size_t)(base_row + r2) * 256 + base_col + c4 * 4;
                *(float4*)&out[off] = v;
            }
        } // p
    } // jx
}

extern "C" void kernel_launch(void* const* d_in, const int* in_sizes, int n_in,
                              void* d_out, int out_size, void* d_ws, size_t ws_size,
                              hipStream_t stream) {
    const float* x    = (const float*)d_in[0];
    const float* f_in = (const float*)d_in[1];
    const float* f_tl = (const float*)d_in[2];
    const float* f_tr = (const float*)d_in[3];
    const float* f_bl = (const float*)d_in[4];
    const float* f_br = (const float*)d_in[5];
    const float* sc   = (const float*)d_in[6];
    const float* hw   = (const float*)d_in[7];
    const float* hb   = (const float*)d_in[8];
    float* out = (float*)d_out;

    dim3 grid(64, 16, 2);
    qtree_kernel<<<grid, NTHR, 0, stream>>>(x, f_in, f_tl, f_tr, f_bl, f_br, sc, hw, hb, out);
}

// Round 3
// 393.854 us; speedup vs baseline: 1.1404x; 1.0711x over previous
//
#include <hip/hip_runtime.h>

constexpr int NTHR = 256;
constexpr int BW   = 4;      // batches per wave (R8: was 2)

typedef short  short8 __attribute__((ext_vector_type(8)));  // 8 bf16 (4 VGPRs)
typedef float  f32x4  __attribute__((ext_vector_type(4)));

// factor row offsets per level: L0:0  L1:1  L2:5  L3:21  L4:85  L5:341
// Zero-barrier design: each wave owns BW batches and the whole tree for them.
// All LDS buffers are wave-private (one aliased pool); intra-wave LDS ordering
// is guaranteed by compiler-inserted lgkmcnt waits. No __syncthreads.
//
// R6/R7 lesson: body needs ~80+ arch VGPRs; caps below 4 waves/EU (128) force
//   catastrophic inner-loop scratch spills (FETCH 28->294MB). Occupancy via
//   register squeeze is a dead end; 16 waves/CU is the wall.
// R8: double per-wave ILP instead. BW 2->4 (4 indep accum chains per stage),
//   grid 2048->1024 blocks = exactly 4 resident/CU = one round, zero drain.
//   LDS 36.9KB/block -> 4 blocks/CU. launch_bounds(256,4) = proven-safe cap.

__device__ __forceinline__ unsigned short f2bf(float f) {
    union { float f; unsigned u; } v; v.f = f;
    unsigned r = v.u + 0x7FFFu + ((v.u >> 16) & 1u);   // RNE
    return (unsigned short)(r >> 16);
}

// lat[b][r] = scale[fo][r] * dot64(f_in[fo][r], xin[b])   (b=0..3, r=0..15)
// two coalesced passes of the proven (b2 x r16 x h2) pattern; fir loads CSE
// across passes (same row), xb differs.
__device__ __forceinline__ void wlat(const float* __restrict__ f_in,
                                     const float* __restrict__ scale,
                                     int fo,
                                     const float (*xin)[64],   // wave-private LDS [BW][64]
                                     float (*lat)[16],         // wave-private LDS [BW][16]
                                     int lane)
{
    const int bh = lane >> 5;         // batch-within-pass
    const int r  = (lane >> 1) & 15;  // 0..15
    const int h  = lane & 1;          // half of dot
    const float4* fir = (const float4*)(f_in + (size_t)fo * 1024 + r * 64 + h * 32);
    const float   sc  = scale[fo * 16 + r];
#pragma unroll
    for (int bp = 0; bp < BW; bp += 2) {
        const int b = bp + bh;
        const float4* xb = (const float4*)(&xin[b][0] + h * 32);
        float p = 0.f;
#pragma unroll
        for (int i = 0; i < 8; ++i) {
            const float4 a = fir[i], c = xb[i];
            p += a.x * c.x + a.y * c.y + a.z * c.z + a.w * c.w;
        }
        p += __shfl_xor(p, 1);
        if (h == 0) lat[b][r] = p * sc;
    }
}

// xout[b][o] = xin[b][o] + sum_r lat[b][r] * fd[r][o]   (b=0..3)
__device__ __forceinline__ void wchild(const float* __restrict__ fd,
                                       const float (*xin)[64],
                                       const float (*lat)[16],
                                       float (*xout)[64],
                                       int lane)
{
    const int o = lane;
    float f[16];
#pragma unroll
    for (int r = 0; r < 16; ++r) f[r] = fd[r * 64 + o];
#pragma unroll
    for (int b = 0; b < BW; ++b) {
        float acc = xin[b][o];
#pragma unroll
        for (int r = 0; r < 16; ++r) acc += lat[b][r] * f[r];
        xout[b][o] = acc;
    }
}

// leaf rows n = b*8 + nbase (bf16, stride 72 shorts), b=0..3 -> 32 rows
__device__ __forceinline__ void wchild_leaf(const float* __restrict__ fd,
                                            const float (*xin)[64],
                                            const float (*lat)[16],
                                            unsigned short* leaf,   // [32][72]
                                            int nbase,
                                            int lane)
{
    const int o = lane;
    float f[16];
#pragma unroll
    for (int r = 0; r < 16; ++r) f[r] = fd[r * 64 + o];
#pragma unroll
    for (int b = 0; b < BW; ++b) {
        float acc = xin[b][o];
#pragma unroll
        for (int r = 0; r < 16; ++r) acc += lat[b][r] * f[r];
        leaf[(b * 8 + nbase) * 72 + o] = f2bf(acc);
    }
}

// min-waves/EU = 4 -> VGPR cap 128 (tighter caps spill: R6/R7 evidence)
__global__ __launch_bounds__(NTHR, 4)
void qtree_kernel(const float* __restrict__ x,      // [128][64]
                  const float* __restrict__ f_in,   // [1365][16][64]
                  const float* __restrict__ f_tl,
                  const float* __restrict__ f_tr,
                  const float* __restrict__ f_bl,
                  const float* __restrict__ f_br,
                  const float* __restrict__ scale,  // [1365][16]
                  const float* __restrict__ head_w, // [48][64]
                  const float* __restrict__ head_b, // [48]
                  float* __restrict__ out)          // [128][3][256][256]
{
    // Per-wave aliased pool, 2304 floats = 9216 B:
    //   [0..1663]  region (lifetime-aliased):
    //              phase A: xa[4][64] @0, xb[4][64] @256   (tree path, dead after L3)
    //              phase B: leaf[32][72] shorts @0 (1152 f) + x5[2*4][64] @1152 (512 f)
    //              phase C: sy[1536] @0                     (output staging)
    //   [1664..2175] x4[2*4][64]  (L3 children, live across both jx)
    //   [2176..2239] lat[4][16]
    //   [2240..2303] lat4[4][16]  (L4 latent, survives L5 wlat overwrites of lat)
    // Total LDS: 4*9216 + 192 (s_hb) = 37056 B -> 4 blocks/CU (=160KB budget).
    __shared__ __align__(16) float s_pool[4][2304];
    __shared__ float s_hb[48];

    const int tid  = threadIdx.x;
    const int wv   = tid >> 6;     // wave = 4-batch group
    const int lane = tid & 63;
    const int n    = lane & 15;    // MFMA N index (leaf row in tile)
    const int q    = lane >> 4;    // quad
    const int n3   = blockIdx.x;   // 0..63  level-3 node (y3*8+x3)
    const int bg   = blockIdx.y;   // 0..7   batch group of 16
    const int jy   = blockIdx.z;   // 0..1
    const int y3   = n3 >> 3, x3 = n3 & 7;

    const float* fdir[4] = { f_tl, f_tr, f_bl, f_br };

    float* P = s_pool[wv];
    float (*xa)[64]  = (float(*)[64])P;            // region phase A
    float (*xb)[64]  = (float(*)[64])(P + 256);
    unsigned short* leaf = (unsigned short*)P;     // region phase B [32][72]
    float (*x5)[64]  = (float(*)[64])(P + 1152);   // region phase B, rows dx2*4+b
    float* sy        = P;                          // region phase C [1536]
    float (*x4)[64]  = (float(*)[64])(P + 1664);   // rows jx*4+b
    float (*lat)[16] = (float(*)[16])(P + 2176);
    float (*lat4)[16]= (float(*)[16])(P + 2240);

    // head bias -> LDS (each wave writes identical values: benign race,
    // own-wave write-then-read is ordered; no barrier needed)
    if (lane < 48) s_hb[lane] = head_b[lane];

    // ---- per-lane head state (reused by all 8 head-tile pairs) ----
    short8 afrag[3][2];
#pragma unroll
    for (int mt = 0; mt < 3; ++mt)
#pragma unroll
        for (int kc = 0; kc < 2; ++kc) {
            const float* src = head_w + (mt * 16 + n) * 64 + kc * 32 + q * 8;
            short8 a;
#pragma unroll
            for (int j = 0; j < 8; ++j) a[j] = (short)f2bf(src[j]);
            afrag[mt][kc] = a;
        }

    // s_y scatter offsets for tile t=0 (add t*768 at use): leaf n -> (lb, dx2, c)
    // o = mt*16 + q*4 + r; packed 2x16b per u32 (offsets < 1536)
    const int lb = n >> 3, ldx = (n >> 2) & 1, lc = n & 3;
    const int lcy = lc >> 1, lcx = lc & 1;
    const int sy_base = lb * 384 + lcy * 64 + ldx * 8 + lcx * 4;
    unsigned sy_pk[6];
#pragma unroll
    for (int i = 0; i < 6; ++i) {
        unsigned lohi[2];
#pragma unroll
        for (int j = 0; j < 2; ++j) {
            const int t = 2 * i + j;                      // t = mt*4 + r
            const int o = (t >> 2) * 16 + q * 4 + (t & 3);
            lohi[j] = (unsigned)(sy_base + (o % 3) * 128 + (o / 12) * 16 + ((o / 3) & 3));
        }
        sy_pk[i] = lohi[0] | (lohi[1] << 16);
    }

    // load this wave's 4 batches
#pragma unroll
    for (int b = 0; b < BW; ++b)
        xa[b][lane] = x[(size_t)(bg * 16 + wv * 4 + b) * 64 + lane];

    // ---- path L0 -> L1 -> L2 (single child each) ----
    {
        wlat(f_in, scale, 0, xa, lat, lane);
        const int d = ((y3 >> 2) << 1) | (x3 >> 2);
        wchild(fdir[d], xa, lat, xb, lane);
    }
    {
        const int fo = 1 + ((y3 >> 2) * 2 + (x3 >> 2));
        wlat(f_in, scale, fo, xb, lat, lane);
        const int d = (((y3 >> 1) & 1) << 1) | ((x3 >> 1) & 1);
        wchild(fdir[d] + (size_t)fo * 1024, xb, lat, xa, lane);
    }
    {
        const int fo = 5 + ((y3 >> 1) * 4 + (x3 >> 1));
        wlat(f_in, scale, fo, xa, lat, lane);
        const int d = ((y3 & 1) << 1) | (x3 & 1);
        wchild(fdir[d] + (size_t)fo * 1024, xa, lat, xb, lane);
    }
    // ---- L3: children for this jy-half -> x4 (outside aliased region) ----
    {
        const int fo = 21 + n3;
        wlat(f_in, scale, fo, xb, lat, lane);
#pragma unroll
        for (int jx = 0; jx < 2; ++jx)
            wchild(fdir[2 * jy + jx] + (size_t)fo * 1024, xb, lat, &x4[BW * jx], lane);
    }
    // path xa/xb dead from here; region reused for leaf/x5/sy

    // ---- two L4 subtrees ----
    for (int jx = 0; jx < 2; ++jx) {
        const int y4 = 2 * y3 + jy, x4c = 2 * x3 + jx;
        const int fo4 = 85 + y4 * 16 + x4c;
        wlat(f_in, scale, fo4, &x4[BW * jx], lat4, lane);  // L4 latent persists in lat4

        // ---- 2 head-tile-pairs per subtree: p halves; children recomputed per p ----
        for (int p = 0; p < 2; ++p) {
#pragma unroll
            for (int dx2 = 0; dx2 < 2; ++dx2)
                wchild(fdir[2 * p + dx2] + (size_t)fo4 * 1024, &x4[BW * jx], lat4,
                       &x5[BW * dx2], lane);
#pragma unroll
            for (int dx2 = 0; dx2 < 2; ++dx2) {
                const int fo5 = 341 + (2 * y4 + p) * 32 + (2 * x4c + dx2);
                wlat(f_in, scale, fo5, &x5[BW * dx2], lat, lane);
#pragma unroll
                for (int c = 0; c < 4; ++c)
                    wchild_leaf(fdir[c] + (size_t)fo5 * 1024, &x5[BW * dx2], lat,
                                leaf, dx2 * 4 + c, lane);
            }

            // MFMA head: 32 leaf rows (2 tiles of 16) x 48 outs, K=64
            f32x4 acc[2][3];
#pragma unroll
            for (int t = 0; t < 2; ++t)
#pragma unroll
                for (int mt = 0; mt < 3; ++mt)
                    acc[t][mt] = *(const f32x4*)&s_hb[mt * 16 + q * 4];
#pragma unroll
            for (int kc = 0; kc < 2; ++kc)
#pragma unroll
                for (int t = 0; t < 2; ++t) {
                    const short8 bfrag = *(const short8*)&leaf[(t * 16 + n) * 72 + kc * 32 + q * 8];
#pragma unroll
                    for (int mt = 0; mt < 3; ++mt)
                        acc[t][mt] = __builtin_amdgcn_mfma_f32_16x16x32_bf16(afrag[mt][kc], bfrag, acc[t][mt], 0, 0, 0);
                }

            // stage y: [4b][3ch][8r][16px]  (sy aliases leaf/x5 -- both dead now)
#pragma unroll
            for (int t = 0; t < 2; ++t)
#pragma unroll
                for (int mt = 0; mt < 3; ++mt)
#pragma unroll
                    for (int r = 0; r < 4; ++r) {
                        const int u = mt * 4 + r;
                        const int ofs = ((sy_pk[u >> 1] >> (16 * (u & 1))) & 0xffff) + t * 768;
                        sy[ofs] = acc[t][mt][r];
                    }

            // full-line stores: rows of 16 px (64 B); 384 float4 chunks = 6/lane
            const int base_row = (4 * y3 + 2 * jy + p) * 8;
            const int base_col = (4 * x3 + 2 * jx) * 8;
#pragma unroll
            for (int s = 0; s < 6; ++s) {
                const int i  = lane + 64 * s;      // 0..383 float4 chunks
                const int c4 = i & 3;
                const int r2 = (i >> 2) & 7;
                const int bc = i >> 5;             // b*3+ch, 0..11
                const float4 v = *(const float4*)&sy[(bc * 8 + r2) * 16 + c4 * 4];
                const size_t off = ((size_t)((bg * 16 + wv * 4 + bc / 3) * 3 + (bc % 3))) * 65536
                                 + (size_t)(base_row + r2) * 256 + base_col + c4 * 4;
                *(float4*)&out[off] = v;
            }
        } // p
    } // jx
}

extern "C" void kernel_launch(void* const* d_in, const int* in_sizes, int n_in,
                              void* d_out, int out_size, void* d_ws, size_t ws_size,
                              hipStream_t stream) {
    const float* x    = (const float*)d_in[0];
    const float* f_in = (const float*)d_in[1];
    const float* f_tl = (const float*)d_in[2];
    const float* f_tr = (const float*)d_in[3];
    const float* f_bl = (const float*)d_in[4];
    const float* f_br = (const float*)d_in[5];
    const float* sc   = (const float*)d_in[6];
    const float* hw   = (const float*)d_in[7];
    const float* hb   = (const float*)d_in[8];
    float* out = (float*)d_out;

    dim3 grid(64, 8, 2);
    qtree_kernel<<<grid, NTHR, 0, stream>>>(x, f_in, f_tl, f_tr, f_bl, f_br, sc, hw, hb, out);
}

// Round 4
// 389.878 us; speedup vs baseline: 1.1520x; 1.0102x over previous
//
#include <hip/hip_runtime.h>

constexpr int NTHR = 256;
constexpr int BW   = 4;      // batches per wave (R8: was 2)

typedef short  short8 __attribute__((ext_vector_type(8)));  // 8 bf16 (4 VGPRs)
typedef float  f32x4  __attribute__((ext_vector_type(4)));

// factor row offsets per level: L0:0  L1:1  L2:5  L3:21  L4:85  L5:341
// Zero-barrier design: each wave owns BW batches and the whole tree for them.
// All LDS buffers are wave-private (one aliased pool); intra-wave LDS ordering
// is guaranteed by compiler-inserted lgkmcnt waits. No __syncthreads.
//
// R6/R7/R8 lesson: with __launch_bounds__ present + MFMA in body, the gfx950
//   allocator splits the unified VGPR/AGPR budget 50/50 (reported VGPR =
//   (512/bound)/2 exactly: 3->80, 4->64, 6->40, 8->32). The VALU side then
//   spills (~200-560MB scratch traffic). The body needs ~90+ arch VGPRs.
// R9: NO launch_bounds -- allocator sizes arch VGPRs to demand and AGPRs to
//   the real accumulator need (~32). BW=4 ILP retained (R8 beat R5 even
//   while spilling). LDS 37KB -> 4 blocks/CU possible; VGPR will set 3-4
//   waves/SIMD. Grid 1024 = at most one ragged round.

__device__ __forceinline__ unsigned short f2bf(float f) {
    union { float f; unsigned u; } v; v.f = f;
    unsigned r = v.u + 0x7FFFu + ((v.u >> 16) & 1u);   // RNE
    return (unsigned short)(r >> 16);
}

// lat[b][r] = scale[fo][r] * dot64(f_in[fo][r], xin[b])   (b=0..3, r=0..15)
// two coalesced passes of the proven (b2 x r16 x h2) pattern; fir loads CSE
// across passes (same row), xb differs.
__device__ __forceinline__ void wlat(const float* __restrict__ f_in,
                                     const float* __restrict__ scale,
                                     int fo,
                                     const float (*xin)[64],   // wave-private LDS [BW][64]
                                     float (*lat)[16],         // wave-private LDS [BW][16]
                                     int lane)
{
    const int bh = lane >> 5;         // batch-within-pass
    const int r  = (lane >> 1) & 15;  // 0..15
    const int h  = lane & 1;          // half of dot
    const float4* fir = (const float4*)(f_in + (size_t)fo * 1024 + r * 64 + h * 32);
    const float   sc  = scale[fo * 16 + r];
#pragma unroll
    for (int bp = 0; bp < BW; bp += 2) {
        const int b = bp + bh;
        const float4* xb = (const float4*)(&xin[b][0] + h * 32);
        float p = 0.f;
#pragma unroll
        for (int i = 0; i < 8; ++i) {
            const float4 a = fir[i], c = xb[i];
            p += a.x * c.x + a.y * c.y + a.z * c.z + a.w * c.w;
        }
        p += __shfl_xor(p, 1);
        if (h == 0) lat[b][r] = p * sc;
    }
}

// xout[b][o] = xin[b][o] + sum_r lat[b][r] * fd[r][o]   (b=0..3)
__device__ __forceinline__ void wchild(const float* __restrict__ fd,
                                       const float (*xin)[64],
                                       const float (*lat)[16],
                                       float (*xout)[64],
                                       int lane)
{
    const int o = lane;
    float f[16];
#pragma unroll
    for (int r = 0; r < 16; ++r) f[r] = fd[r * 64 + o];
#pragma unroll
    for (int b = 0; b < BW; ++b) {
        float acc = xin[b][o];
#pragma unroll
        for (int r = 0; r < 16; ++r) acc += lat[b][r] * f[r];
        xout[b][o] = acc;
    }
}

// leaf rows n = b*8 + nbase (bf16, stride 72 shorts), b=0..3 -> 32 rows
__device__ __forceinline__ void wchild_leaf(const float* __restrict__ fd,
                                            const float (*xin)[64],
                                            const float (*lat)[16],
                                            unsigned short* leaf,   // [32][72]
                                            int nbase,
                                            int lane)
{
    const int o = lane;
    float f[16];
#pragma unroll
    for (int r = 0; r < 16; ++r) f[r] = fd[r * 64 + o];
#pragma unroll
    for (int b = 0; b < BW; ++b) {
        float acc = xin[b][o];
#pragma unroll
        for (int r = 0; r < 16; ++r) acc += lat[b][r] * f[r];
        leaf[(b * 8 + nbase) * 72 + o] = f2bf(acc);
    }
}

// NO launch_bounds: avoid the 50/50 VGPR/AGPR forced split (see header note)
__global__
void qtree_kernel(const float* __restrict__ x,      // [128][64]
                  const float* __restrict__ f_in,   // [1365][16][64]
                  const float* __restrict__ f_tl,
                  const float* __restrict__ f_tr,
                  const float* __restrict__ f_bl,
                  const float* __restrict__ f_br,
                  const float* __restrict__ scale,  // [1365][16]
                  const float* __restrict__ head_w, // [48][64]
                  const float* __restrict__ head_b, // [48]
                  float* __restrict__ out)          // [128][3][256][256]
{
    // Per-wave aliased pool, 2304 floats = 9216 B:
    //   [0..1663]  region (lifetime-aliased):
    //              phase A: xa[4][64] @0, xb[4][64] @256   (tree path, dead after L3)
    //              phase B: leaf[32][72] shorts @0 (1152 f) + x5[2*4][64] @1152 (512 f)
    //              phase C: sy[1536] @0                     (output staging)
    //   [1664..2175] x4[2*4][64]  (L3 children, live across both jx)
    //   [2176..2239] lat[4][16]
    //   [2240..2303] lat4[4][16]  (L4 latent, survives L5 wlat overwrites of lat)
    // Total LDS: 4*9216 + 192 (s_hb) = 37056 B -> up to 4 blocks/CU.
    __shared__ __align__(16) float s_pool[4][2304];
    __shared__ float s_hb[48];

    const int tid  = threadIdx.x;
    const int wv   = tid >> 6;     // wave = 4-batch group
    const int lane = tid & 63;
    const int n    = lane & 15;    // MFMA N index (leaf row in tile)
    const int q    = lane >> 4;    // quad
    const int n3   = blockIdx.x;   // 0..63  level-3 node (y3*8+x3)
    const int bg   = blockIdx.y;   // 0..7   batch group of 16
    const int jy   = blockIdx.z;   // 0..1
    const int y3   = n3 >> 3, x3 = n3 & 7;

    const float* fdir[4] = { f_tl, f_tr, f_bl, f_br };

    float* P = s_pool[wv];
    float (*xa)[64]  = (float(*)[64])P;            // region phase A
    float (*xb)[64]  = (float(*)[64])(P + 256);
    unsigned short* leaf = (unsigned short*)P;     // region phase B [32][72]
    float (*x5)[64]  = (float(*)[64])(P + 1152);   // region phase B, rows dx2*4+b
    float* sy        = P;                          // region phase C [1536]
    float (*x4)[64]  = (float(*)[64])(P + 1664);   // rows jx*4+b
    float (*lat)[16] = (float(*)[16])(P + 2176);
    float (*lat4)[16]= (float(*)[16])(P + 2240);

    // head bias -> LDS (each wave writes identical values: benign race,
    // own-wave write-then-read is ordered; no barrier needed)
    if (lane < 48) s_hb[lane] = head_b[lane];

    // ---- per-lane head state (reused by all 8 head-tile pairs) ----
    short8 afrag[3][2];
#pragma unroll
    for (int mt = 0; mt < 3; ++mt)
#pragma unroll
        for (int kc = 0; kc < 2; ++kc) {
            const float* src = head_w + (mt * 16 + n) * 64 + kc * 32 + q * 8;
            short8 a;
#pragma unroll
            for (int j = 0; j < 8; ++j) a[j] = (short)f2bf(src[j]);
            afrag[mt][kc] = a;
        }

    // s_y scatter offsets for tile t=0 (add t*768 at use): leaf n -> (lb, dx2, c)
    // o = mt*16 + q*4 + r; packed 2x16b per u32 (offsets < 1536)
    const int lb = n >> 3, ldx = (n >> 2) & 1, lc = n & 3;
    const int lcy = lc >> 1, lcx = lc & 1;
    const int sy_base = lb * 384 + lcy * 64 + ldx * 8 + lcx * 4;
    unsigned sy_pk[6];
#pragma unroll
    for (int i = 0; i < 6; ++i) {
        unsigned lohi[2];
#pragma unroll
        for (int j = 0; j < 2; ++j) {
            const int t = 2 * i + j;                      // t = mt*4 + r
            const int o = (t >> 2) * 16 + q * 4 + (t & 3);
            lohi[j] = (unsigned)(sy_base + (o % 3) * 128 + (o / 12) * 16 + ((o / 3) & 3));
        }
        sy_pk[i] = lohi[0] | (lohi[1] << 16);
    }

    // load this wave's 4 batches
#pragma unroll
    for (int b = 0; b < BW; ++b)
        xa[b][lane] = x[(size_t)(bg * 16 + wv * 4 + b) * 64 + lane];

    // ---- path L0 -> L1 -> L2 (single child each) ----
    {
        wlat(f_in, scale, 0, xa, lat, lane);
        const int d = ((y3 >> 2) << 1) | (x3 >> 2);
        wchild(fdir[d], xa, lat, xb, lane);
    }
    {
        const int fo = 1 + ((y3 >> 2) * 2 + (x3 >> 2));
        wlat(f_in, scale, fo, xb, lat, lane);
        const int d = (((y3 >> 1) & 1) << 1) | ((x3 >> 1) & 1);
        wchild(fdir[d] + (size_t)fo * 1024, xb, lat, xa, lane);
    }
    {
        const int fo = 5 + ((y3 >> 1) * 4 + (x3 >> 1));
        wlat(f_in, scale, fo, xa, lat, lane);
        const int d = ((y3 & 1) << 1) | (x3 & 1);
        wchild(fdir[d] + (size_t)fo * 1024, xa, lat, xb, lane);
    }
    // ---- L3: children for this jy-half -> x4 (outside aliased region) ----
    {
        const int fo = 21 + n3;
        wlat(f_in, scale, fo, xb, lat, lane);
#pragma unroll
        for (int jx = 0; jx < 2; ++jx)
            wchild(fdir[2 * jy + jx] + (size_t)fo * 1024, xb, lat, &x4[BW * jx], lane);
    }
    // path xa/xb dead from here; region reused for leaf/x5/sy

    // ---- two L4 subtrees ----
    for (int jx = 0; jx < 2; ++jx) {
        const int y4 = 2 * y3 + jy, x4c = 2 * x3 + jx;
        const int fo4 = 85 + y4 * 16 + x4c;
        wlat(f_in, scale, fo4, &x4[BW * jx], lat4, lane);  // L4 latent persists in lat4

        // ---- 2 head-tile-pairs per subtree: p halves; children recomputed per p ----
        for (int p = 0; p < 2; ++p) {
#pragma unroll
            for (int dx2 = 0; dx2 < 2; ++dx2)
                wchild(fdir[2 * p + dx2] + (size_t)fo4 * 1024, &x4[BW * jx], lat4,
                       &x5[BW * dx2], lane);
#pragma unroll
            for (int dx2 = 0; dx2 < 2; ++dx2) {
                const int fo5 = 341 + (2 * y4 + p) * 32 + (2 * x4c + dx2);
                wlat(f_in, scale, fo5, &x5[BW * dx2], lat, lane);
#pragma unroll
                for (int c = 0; c < 4; ++c)
                    wchild_leaf(fdir[c] + (size_t)fo5 * 1024, &x5[BW * dx2], lat,
                                leaf, dx2 * 4 + c, lane);
            }

            // MFMA head: 32 leaf rows (2 tiles of 16) x 48 outs, K=64
            f32x4 acc[2][3];
#pragma unroll
            for (int t = 0; t < 2; ++t)
#pragma unroll
                for (int mt = 0; mt < 3; ++mt)
                    acc[t][mt] = *(const f32x4*)&s_hb[mt * 16 + q * 4];
#pragma unroll
            for (int kc = 0; kc < 2; ++kc)
#pragma unroll
                for (int t = 0; t < 2; ++t) {
                    const short8 bfrag = *(const short8*)&leaf[(t * 16 + n) * 72 + kc * 32 + q * 8];
#pragma unroll
                    for (int mt = 0; mt < 3; ++mt)
                        acc[t][mt] = __builtin_amdgcn_mfma_f32_16x16x32_bf16(afrag[mt][kc], bfrag, acc[t][mt], 0, 0, 0);
                }

            // stage y: [4b][3ch][8r][16px]  (sy aliases leaf/x5 -- both dead now)
#pragma unroll
            for (int t = 0; t < 2; ++t)
#pragma unroll
                for (int mt = 0; mt < 3; ++mt)
#pragma unroll
                    for (int r = 0; r < 4; ++r) {
                        const int u = mt * 4 + r;
                        const int ofs = ((sy_pk[u >> 1] >> (16 * (u & 1))) & 0xffff) + t * 768;
                        sy[ofs] = acc[t][mt][r];
                    }

            // full-line stores: rows of 16 px (64 B); 384 float4 chunks = 6/lane
            const int base_row = (4 * y3 + 2 * jy + p) * 8;
            const int base_col = (4 * x3 + 2 * jx) * 8;
#pragma unroll
            for (int s = 0; s < 6; ++s) {
                const int i  = lane + 64 * s;      // 0..383 float4 chunks
                const int c4 = i & 3;
                const int r2 = (i >> 2) & 7;
                const int bc = i >> 5;             // b*3+ch, 0..11
                const float4 v = *(const float4*)&sy[(bc * 8 + r2) * 16 + c4 * 4];
                const size_t off = ((size_t)((bg * 16 + wv * 4 + bc / 3) * 3 + (bc % 3))) * 65536
                                 + (size_t)(base_row + r2) * 256 + base_col + c4 * 4;
                *(float4*)&out[off] = v;
            }
        } // p
    } // jx
}

extern "C" void kernel_launch(void* const* d_in, const int* in_sizes, int n_in,
                              void* d_out, int out_size, void* d_ws, size_t ws_size,
                              hipStream_t stream) {
    const float* x    = (const float*)d_in[0];
    const float* f_in = (const float*)d_in[1];
    const float* f_tl = (const float*)d_in[2];
    const float* f_tr = (const float*)d_in[3];
    const float* f_bl = (const float*)d_in[4];
    const float* f_br = (const float*)d_in[5];
    const float* sc   = (const float*)d_in[6];
    const float* hw   = (const float*)d_in[7];
    const float* hb   = (const float*)d_in[8];
    float* out = (float*)d_out;

    dim3 grid(64, 8, 2);
    qtree_kernel<<<grid, NTHR, 0, stream>>>(x, f_in, f_tl, f_tr, f_bl, f_br, sc, hw, hb, out);
}

// Round 6
// 294.484 us; speedup vs baseline: 1.5252x; 1.3239x over previous
//
#include <hip/hip_runtime.h>

constexpr int NTHR = 256;
constexpr int BW   = 4;      // batches per wave (R8: was 2)

typedef short  short8 __attribute__((ext_vector_type(8)));  // 8 bf16 (4 VGPRs)
typedef float  f32x4  __attribute__((ext_vector_type(4)));

// factor row offsets per level: L0:0  L1:1  L2:5  L3:21  L4:85  L5:341
// Zero-barrier design: each wave owns BW batches and the whole tree for them.
// All LDS buffers are wave-private (one aliased pool); intra-wave LDS ordering
// is guaranteed by compiler-inserted lgkmcnt waits. No __syncthreads.
//
// Register-allocation ledger (rocprof VGPR_Count vs bound):
//   (256,3)->80  (256,4)->64  (256,6)->40  (256,8)->32  none->64
//   => budget = 512/max(waves-min, 4-from-default-1024-block), split ~half
//      arch/acc when MFMA present. BW=4 body needs ~110 arch VGPRs; anything
//      less round-trips ~210MB scratch (FETCH 247/WRITE 310 vs ideal 30/105).
// R10: __launch_bounds__(256) SINGLE-ARG -- max block 256 threads = 1 wave/SIMD
//   minimum residency, NO min-waves constraint -> full 512 budget, allocator
//   sizes to demand (~136 total, 3 waves/SIMD). The only untried config.
// R11: resubmit of R10 verbatim -- R10's bench was an infra failure
//   ("MI355X container failed twice"), no counters produced; no evidence to
//   justify a kernel change.

__device__ __forceinline__ unsigned short f2bf(float f) {
    union { float f; unsigned u; } v; v.f = f;
    unsigned r = v.u + 0x7FFFu + ((v.u >> 16) & 1u);   // RNE
    return (unsigned short)(r >> 16);
}

// lat[b][r] = scale[fo][r] * dot64(f_in[fo][r], xin[b])   (b=0..3, r=0..15)
// two coalesced passes of the proven (b2 x r16 x h2) pattern; fir loads CSE
// across passes (same row), xb differs.
__device__ __forceinline__ void wlat(const float* __restrict__ f_in,
                                     const float* __restrict__ scale,
                                     int fo,
                                     const float (*xin)[64],   // wave-private LDS [BW][64]
                                     float (*lat)[16],         // wave-private LDS [BW][16]
                                     int lane)
{
    const int bh = lane >> 5;         // batch-within-pass
    const int r  = (lane >> 1) & 15;  // 0..15
    const int h  = lane & 1;          // half of dot
    const float4* fir = (const float4*)(f_in + (size_t)fo * 1024 + r * 64 + h * 32);
    const float   sc  = scale[fo * 16 + r];
#pragma unroll
    for (int bp = 0; bp < BW; bp += 2) {
        const int b = bp + bh;
        const float4* xb = (const float4*)(&xin[b][0] + h * 32);
        float p = 0.f;
#pragma unroll
        for (int i = 0; i < 8; ++i) {
            const float4 a = fir[i], c = xb[i];
            p += a.x * c.x + a.y * c.y + a.z * c.z + a.w * c.w;
        }
        p += __shfl_xor(p, 1);
        if (h == 0) lat[b][r] = p * sc;
    }
}

// xout[b][o] = xin[b][o] + sum_r lat[b][r] * fd[r][o]   (b=0..3)
__device__ __forceinline__ void wchild(const float* __restrict__ fd,
                                       const float (*xin)[64],
                                       const float (*lat)[16],
                                       float (*xout)[64],
                                       int lane)
{
    const int o = lane;
    float f[16];
#pragma unroll
    for (int r = 0; r < 16; ++r) f[r] = fd[r * 64 + o];
#pragma unroll
    for (int b = 0; b < BW; ++b) {
        float acc = xin[b][o];
#pragma unroll
        for (int r = 0; r < 16; ++r) acc += lat[b][r] * f[r];
        xout[b][o] = acc;
    }
}

// leaf rows n = b*8 + nbase (bf16, stride 72 shorts), b=0..3 -> 32 rows
__device__ __forceinline__ void wchild_leaf(const float* __restrict__ fd,
                                            const float (*xin)[64],
                                            const float (*lat)[16],
                                            unsigned short* leaf,   // [32][72]
                                            int nbase,
                                            int lane)
{
    const int o = lane;
    float f[16];
#pragma unroll
    for (int r = 0; r < 16; ++r) f[r] = fd[r * 64 + o];
#pragma unroll
    for (int b = 0; b < BW; ++b) {
        float acc = xin[b][o];
#pragma unroll
        for (int r = 0; r < 16; ++r) acc += lat[b][r] * f[r];
        leaf[(b * 8 + nbase) * 72 + o] = f2bf(acc);
    }
}

// single-arg: max 256 threads/block, NO min-waves constraint -> full reg budget
__global__ __launch_bounds__(NTHR)
void qtree_kernel(const float* __restrict__ x,      // [128][64]
                  const float* __restrict__ f_in,   // [1365][16][64]
                  const float* __restrict__ f_tl,
                  const float* __restrict__ f_tr,
                  const float* __restrict__ f_bl,
                  const float* __restrict__ f_br,
                  const float* __restrict__ scale,  // [1365][16]
                  const float* __restrict__ head_w, // [48][64]
                  const float* __restrict__ head_b, // [48]
                  float* __restrict__ out)          // [128][3][256][256]
{
    // Per-wave aliased pool, 2304 floats = 9216 B:
    //   [0..1663]  region (lifetime-aliased):
    //              phase A: xa[4][64] @0, xb[4][64] @256   (tree path, dead after L3)
    //              phase B: leaf[32][72] shorts @0 (1152 f) + x5[2*4][64] @1152 (512 f)
    //              phase C: sy[1536] @0                     (output staging)
    //   [1664..2175] x4[2*4][64]  (L3 children, live across both jx)
    //   [2176..2239] lat[4][16]
    //   [2240..2303] lat4[4][16]  (L4 latent, survives L5 wlat overwrites of lat)
    // Total LDS: 4*9216 + 192 (s_hb) = 37056 B.
    __shared__ __align__(16) float s_pool[4][2304];
    __shared__ float s_hb[48];

    const int tid  = threadIdx.x;
    const int wv   = tid >> 6;     // wave = 4-batch group
    const int lane = tid & 63;
    const int n    = lane & 15;    // MFMA N index (leaf row in tile)
    const int q    = lane >> 4;    // quad
    const int n3   = blockIdx.x;   // 0..63  level-3 node (y3*8+x3)
    const int bg   = blockIdx.y;   // 0..7   batch group of 16
    const int jy   = blockIdx.z;   // 0..1
    const int y3   = n3 >> 3, x3 = n3 & 7;

    const float* fdir[4] = { f_tl, f_tr, f_bl, f_br };

    float* P = s_pool[wv];
    float (*xa)[64]  = (float(*)[64])P;            // region phase A
    float (*xb)[64]  = (float(*)[64])(P + 256);
    unsigned short* leaf = (unsigned short*)P;     // region phase B [32][72]
    float (*x5)[64]  = (float(*)[64])(P + 1152);   // region phase B, rows dx2*4+b
    float* sy        = P;                          // region phase C [1536]
    float (*x4)[64]  = (float(*)[64])(P + 1664);   // rows jx*4+b
    float (*lat)[16] = (float(*)[16])(P + 2176);
    float (*lat4)[16]= (float(*)[16])(P + 2240);

    // head bias -> LDS (each wave writes identical values: benign race,
    // own-wave write-then-read is ordered; no barrier needed)
    if (lane < 48) s_hb[lane] = head_b[lane];

    // ---- per-lane head state (reused by all 8 head-tile pairs) ----
    short8 afrag[3][2];
#pragma unroll
    for (int mt = 0; mt < 3; ++mt)
#pragma unroll
        for (int kc = 0; kc < 2; ++kc) {
            const float* src = head_w + (mt * 16 + n) * 64 + kc * 32 + q * 8;
            short8 a;
#pragma unroll
            for (int j = 0; j < 8; ++j) a[j] = (short)f2bf(src[j]);
            afrag[mt][kc] = a;
        }

    // s_y scatter offsets for tile t=0 (add t*768 at use): leaf n -> (lb, dx2, c)
    // o = mt*16 + q*4 + r; packed 2x16b per u32 (offsets < 1536)
    const int lb = n >> 3, ldx = (n >> 2) & 1, lc = n & 3;
    const int lcy = lc >> 1, lcx = lc & 1;
    const int sy_base = lb * 384 + lcy * 64 + ldx * 8 + lcx * 4;
    unsigned sy_pk[6];
#pragma unroll
    for (int i = 0; i < 6; ++i) {
        unsigned lohi[2];
#pragma unroll
        for (int j = 0; j < 2; ++j) {
            const int t = 2 * i + j;                      // t = mt*4 + r
            const int o = (t >> 2) * 16 + q * 4 + (t & 3);
            lohi[j] = (unsigned)(sy_base + (o % 3) * 128 + (o / 12) * 16 + ((o / 3) & 3));
        }
        sy_pk[i] = lohi[0] | (lohi[1] << 16);
    }

    // load this wave's 4 batches
#pragma unroll
    for (int b = 0; b < BW; ++b)
        xa[b][lane] = x[(size_t)(bg * 16 + wv * 4 + b) * 64 + lane];

    // ---- path L0 -> L1 -> L2 (single child each) ----
    {
        wlat(f_in, scale, 0, xa, lat, lane);
        const int d = ((y3 >> 2) << 1) | (x3 >> 2);
        wchild(fdir[d], xa, lat, xb, lane);
    }
    {
        const int fo = 1 + ((y3 >> 2) * 2 + (x3 >> 2));
        wlat(f_in, scale, fo, xb, lat, lane);
        const int d = (((y3 >> 1) & 1) << 1) | ((x3 >> 1) & 1);
        wchild(fdir[d] + (size_t)fo * 1024, xb, lat, xa, lane);
    }
    {
        const int fo = 5 + ((y3 >> 1) * 4 + (x3 >> 1));
        wlat(f_in, scale, fo, xa, lat, lane);
        const int d = ((y3 & 1) << 1) | (x3 & 1);
        wchild(fdir[d] + (size_t)fo * 1024, xa, lat, xb, lane);
    }
    // ---- L3: children for this jy-half -> x4 (outside aliased region) ----
    {
        const int fo = 21 + n3;
        wlat(f_in, scale, fo, xb, lat, lane);
#pragma unroll
        for (int jx = 0; jx < 2; ++jx)
            wchild(fdir[2 * jy + jx] + (size_t)fo * 1024, xb, lat, &x4[BW * jx], lane);
    }
    // path xa/xb dead from here; region reused for leaf/x5/sy

    // ---- two L4 subtrees ----
    for (int jx = 0; jx < 2; ++jx) {
        const int y4 = 2 * y3 + jy, x4c = 2 * x3 + jx;
        const int fo4 = 85 + y4 * 16 + x4c;
        wlat(f_in, scale, fo4, &x4[BW * jx], lat4, lane);  // L4 latent persists in lat4

        // ---- 2 head-tile-pairs per subtree: p halves; children recomputed per p ----
        for (int p = 0; p < 2; ++p) {
#pragma unroll
            for (int dx2 = 0; dx2 < 2; ++dx2)
                wchild(fdir[2 * p + dx2] + (size_t)fo4 * 1024, &x4[BW * jx], lat4,
                       &x5[BW * dx2], lane);
#pragma unroll
            for (int dx2 = 0; dx2 < 2; ++dx2) {
                const int fo5 = 341 + (2 * y4 + p) * 32 + (2 * x4c + dx2);
                wlat(f_in, scale, fo5, &x5[BW * dx2], lat, lane);
#pragma unroll
                for (int c = 0; c < 4; ++c)
                    wchild_leaf(fdir[c] + (size_t)fo5 * 1024, &x5[BW * dx2], lat,
                                leaf, dx2 * 4 + c, lane);
            }

            // MFMA head: 32 leaf rows (2 tiles of 16) x 48 outs, K=64
            f32x4 acc[2][3];
#pragma unroll
            for (int t = 0; t < 2; ++t)
#pragma unroll
                for (int mt = 0; mt < 3; ++mt)
                    acc[t][mt] = *(const f32x4*)&s_hb[mt * 16 + q * 4];
#pragma unroll
            for (int kc = 0; kc < 2; ++kc)
#pragma unroll
                for (int t = 0; t < 2; ++t) {
                    const short8 bfrag = *(const short8*)&leaf[(t * 16 + n) * 72 + kc * 32 + q * 8];
#pragma unroll
                    for (int mt = 0; mt < 3; ++mt)
                        acc[t][mt] = __builtin_amdgcn_mfma_f32_16x16x32_bf16(afrag[mt][kc], bfrag, acc[t][mt], 0, 0, 0);
                }

            // stage y: [4b][3ch][8r][16px]  (sy aliases leaf/x5 -- both dead now)
#pragma unroll
            for (int t = 0; t < 2; ++t)
#pragma unroll
                for (int mt = 0; mt < 3; ++mt)
#pragma unroll
                    for (int r = 0; r < 4; ++r) {
                        const int u = mt * 4 + r;
                        const int ofs = ((sy_pk[u >> 1] >> (16 * (u & 1))) & 0xffff) + t * 768;
                        sy[ofs] = acc[t][mt][r];
                    }

            // full-line stores: rows of 16 px (64 B); 384 float4 chunks = 6/lane
            const int base_row = (4 * y3 + 2 * jy + p) * 8;
            const int base_col = (4 * x3 + 2 * jx) * 8;
#pragma unroll
            for (int s = 0; s < 6; ++s) {
                const int i  = lane + 64 * s;      // 0..383 float4 chunks
                const int c4 = i & 3;
                const int r2 = (i >> 2) & 7;
                const int bc = i >> 5;             // b*3+ch, 0..11
                const float4 v = *(const float4*)&sy[(bc * 8 + r2) * 16 + c4 * 4];
                const size_t off = ((size_t)((bg * 16 + wv * 4 + bc / 3) * 3 + (bc % 3))) * 65536
                                 + (size_t)(base_row + r2) * 256 + base_col + c4 * 4;
                *(float4*)&out[off] = v;
            }
        } // p
    } // jx
}

extern "C" void kernel_launch(void* const* d_in, const int* in_sizes, int n_in,
                              void* d_out, int out_size, void* d_ws, size_t ws_size,
                              hipStream_t stream) {
    const float* x    = (const float*)d_in[0];
    const float* f_in = (const float*)d_in[1];
    const float* f_tl = (const float*)d_in[2];
    const float* f_tr = (const float*)d_in[3];
    const float* f_bl = (const float*)d_in[4];
    const float* f_br = (const float*)d_in[5];
    const float* sc   = (const float*)d_in[6];
    const float* hw   = (const float*)d_in[7];
    const float* hb   = (const float*)d_in[8];
    float* out = (float*)d_out;

    dim3 grid(64, 8, 2);
    qtree_kernel<<<grid, NTHR, 0, stream>>>(x, f_in, f_tl, f_tr, f_bl, f_br, sc, hw, hb, out);
}

// Round 7
// 256.166 us; speedup vs baseline: 1.7534x; 1.1496x over previous
//
#include <hip/hip_runtime.h>

constexpr int NTHR = 256;
constexpr int BW   = 4;      // batches per wave (R8: was 2)

typedef short  short8 __attribute__((ext_vector_type(8)));  // 8 bf16 (4 VGPRs)
typedef float  f32x4  __attribute__((ext_vector_type(4)));

// factor row offsets per level: L0:0  L1:1  L2:5  L3:21  L4:85  L5:341
// Zero-barrier design: each wave owns BW batches and the whole tree for them.
// All LDS buffers are wave-private (one aliased pool); intra-wave LDS ordering
// is guaranteed by compiler-inserted lgkmcnt waits. No __syncthreads.
//
// Register-allocation ledger (rocprof VGPR_Count vs bound):
//   (256,3)->80  (256,4)->64  (256,6)->40  (256,8)->32  none->64
//   (256) single-arg -> 132, FETCH 28MB (zero spill), dur 192us, occ 11%
//   => arch VGPRs = (512/min-waves)/2 when MFMA present (even unified split).
//      Single-arg: allocator sized BOTH halves to demand -> total >256/wave
//      -> 1 block/CU -> occupancy 11%, latency-exposed.
// R12: __launch_bounds__(256,2) -- budget 256/wave = 128 arch + 128 acc.
//   Arch demand 132 -> squeeze of 4 regs (remat, not spill cliff; cliff is
//   ~20+ under demand per R5/R8 evidence). 8 waves/CU = 2 blocks/CU, 2x R11
//   residency. Tripwire: FETCH >> 30MB means the squeeze spilled.

__device__ __forceinline__ unsigned short f2bf(float f) {
    union { float f; unsigned u; } v; v.f = f;
    unsigned r = v.u + 0x7FFFu + ((v.u >> 16) & 1u);   // RNE
    return (unsigned short)(r >> 16);
}

// lat[b][r] = scale[fo][r] * dot64(f_in[fo][r], xin[b])   (b=0..3, r=0..15)
// two coalesced passes of the proven (b2 x r16 x h2) pattern; fir loads CSE
// across passes (same row), xb differs.
__device__ __forceinline__ void wlat(const float* __restrict__ f_in,
                                     const float* __restrict__ scale,
                                     int fo,
                                     const float (*xin)[64],   // wave-private LDS [BW][64]
                                     float (*lat)[16],         // wave-private LDS [BW][16]
                                     int lane)
{
    const int bh = lane >> 5;         // batch-within-pass
    const int r  = (lane >> 1) & 15;  // 0..15
    const int h  = lane & 1;          // half of dot
    const float4* fir = (const float4*)(f_in + (size_t)fo * 1024 + r * 64 + h * 32);
    const float   sc  = scale[fo * 16 + r];
#pragma unroll
    for (int bp = 0; bp < BW; bp += 2) {
        const int b = bp + bh;
        const float4* xb = (const float4*)(&xin[b][0] + h * 32);
        float p = 0.f;
#pragma unroll
        for (int i = 0; i < 8; ++i) {
            const float4 a = fir[i], c = xb[i];
            p += a.x * c.x + a.y * c.y + a.z * c.z + a.w * c.w;
        }
        p += __shfl_xor(p, 1);
        if (h == 0) lat[b][r] = p * sc;
    }
}

// xout[b][o] = xin[b][o] + sum_r lat[b][r] * fd[r][o]   (b=0..3)
__device__ __forceinline__ void wchild(const float* __restrict__ fd,
                                       const float (*xin)[64],
                                       const float (*lat)[16],
                                       float (*xout)[64],
                                       int lane)
{
    const int o = lane;
    float f[16];
#pragma unroll
    for (int r = 0; r < 16; ++r) f[r] = fd[r * 64 + o];
#pragma unroll
    for (int b = 0; b < BW; ++b) {
        float acc = xin[b][o];
#pragma unroll
        for (int r = 0; r < 16; ++r) acc += lat[b][r] * f[r];
        xout[b][o] = acc;
    }
}

// leaf rows n = b*8 + nbase (bf16, stride 72 shorts), b=0..3 -> 32 rows
__device__ __forceinline__ void wchild_leaf(const float* __restrict__ fd,
                                            const float (*xin)[64],
                                            const float (*lat)[16],
                                            unsigned short* leaf,   // [32][72]
                                            int nbase,
                                            int lane)
{
    const int o = lane;
    float f[16];
#pragma unroll
    for (int r = 0; r < 16; ++r) f[r] = fd[r * 64 + o];
#pragma unroll
    for (int b = 0; b < BW; ++b) {
        float acc = xin[b][o];
#pragma unroll
        for (int r = 0; r < 16; ++r) acc += lat[b][r] * f[r];
        leaf[(b * 8 + nbase) * 72 + o] = f2bf(acc);
    }
}

// (256,2): 256-reg/wave budget = 128 arch + 128 acc; 2 blocks/CU
__global__ __launch_bounds__(NTHR, 2)
void qtree_kernel(const float* __restrict__ x,      // [128][64]
                  const float* __restrict__ f_in,   // [1365][16][64]
                  const float* __restrict__ f_tl,
                  const float* __restrict__ f_tr,
                  const float* __restrict__ f_bl,
                  const float* __restrict__ f_br,
                  const float* __restrict__ scale,  // [1365][16]
                  const float* __restrict__ head_w, // [48][64]
                  const float* __restrict__ head_b, // [48]
                  float* __restrict__ out)          // [128][3][256][256]
{
    // Per-wave aliased pool, 2304 floats = 9216 B:
    //   [0..1663]  region (lifetime-aliased):
    //              phase A: xa[4][64] @0, xb[4][64] @256   (tree path, dead after L3)
    //              phase B: leaf[32][72] shorts @0 (1152 f) + x5[2*4][64] @1152 (512 f)
    //              phase C: sy[1536] @0                     (output staging)
    //   [1664..2175] x4[2*4][64]  (L3 children, live across both jx)
    //   [2176..2239] lat[4][16]
    //   [2240..2303] lat4[4][16]  (L4 latent, survives L5 wlat overwrites of lat)
    // Total LDS: 4*9216 + 192 (s_hb) = 37056 B; 2 blocks/CU = 75KB.
    __shared__ __align__(16) float s_pool[4][2304];
    __shared__ float s_hb[48];

    const int tid  = threadIdx.x;
    const int wv   = tid >> 6;     // wave = 4-batch group
    const int lane = tid & 63;
    const int n    = lane & 15;    // MFMA N index (leaf row in tile)
    const int q    = lane >> 4;    // quad
    const int n3   = blockIdx.x;   // 0..63  level-3 node (y3*8+x3)
    const int bg   = blockIdx.y;   // 0..7   batch group of 16
    const int jy   = blockIdx.z;   // 0..1
    const int y3   = n3 >> 3, x3 = n3 & 7;

    const float* fdir[4] = { f_tl, f_tr, f_bl, f_br };

    float* P = s_pool[wv];
    float (*xa)[64]  = (float(*)[64])P;            // region phase A
    float (*xb)[64]  = (float(*)[64])(P + 256);
    unsigned short* leaf = (unsigned short*)P;     // region phase B [32][72]
    float (*x5)[64]  = (float(*)[64])(P + 1152);   // region phase B, rows dx2*4+b
    float* sy        = P;                          // region phase C [1536]
    float (*x4)[64]  = (float(*)[64])(P + 1664);   // rows jx*4+b
    float (*lat)[16] = (float(*)[16])(P + 2176);
    float (*lat4)[16]= (float(*)[16])(P + 2240);

    // head bias -> LDS (each wave writes identical values: benign race,
    // own-wave write-then-read is ordered; no barrier needed)
    if (lane < 48) s_hb[lane] = head_b[lane];

    // ---- per-lane head state (reused by all 8 head-tile pairs) ----
    short8 afrag[3][2];
#pragma unroll
    for (int mt = 0; mt < 3; ++mt)
#pragma unroll
        for (int kc = 0; kc < 2; ++kc) {
            const float* src = head_w + (mt * 16 + n) * 64 + kc * 32 + q * 8;
            short8 a;
#pragma unroll
            for (int j = 0; j < 8; ++j) a[j] = (short)f2bf(src[j]);
            afrag[mt][kc] = a;
        }

    // s_y scatter offsets for tile t=0 (add t*768 at use): leaf n -> (lb, dx2, c)
    // o = mt*16 + q*4 + r; packed 2x16b per u32 (offsets < 1536)
    const int lb = n >> 3, ldx = (n >> 2) & 1, lc = n & 3;
    const int lcy = lc >> 1, lcx = lc & 1;
    const int sy_base = lb * 384 + lcy * 64 + ldx * 8 + lcx * 4;
    unsigned sy_pk[6];
#pragma unroll
    for (int i = 0; i < 6; ++i) {
        unsigned lohi[2];
#pragma unroll
        for (int j = 0; j < 2; ++j) {
            const int t = 2 * i + j;                      // t = mt*4 + r
            const int o = (t >> 2) * 16 + q * 4 + (t & 3);
            lohi[j] = (unsigned)(sy_base + (o % 3) * 128 + (o / 12) * 16 + ((o / 3) & 3));
        }
        sy_pk[i] = lohi[0] | (lohi[1] << 16);
    }

    // load this wave's 4 batches
#pragma unroll
    for (int b = 0; b < BW; ++b)
        xa[b][lane] = x[(size_t)(bg * 16 + wv * 4 + b) * 64 + lane];

    // ---- path L0 -> L1 -> L2 (single child each) ----
    {
        wlat(f_in, scale, 0, xa, lat, lane);
        const int d = ((y3 >> 2) << 1) | (x3 >> 2);
        wchild(fdir[d], xa, lat, xb, lane);
    }
    {
        const int fo = 1 + ((y3 >> 2) * 2 + (x3 >> 2));
        wlat(f_in, scale, fo, xb, lat, lane);
        const int d = (((y3 >> 1) & 1) << 1) | ((x3 >> 1) & 1);
        wchild(fdir[d] + (size_t)fo * 1024, xb, lat, xa, lane);
    }
    {
        const int fo = 5 + ((y3 >> 1) * 4 + (x3 >> 1));
        wlat(f_in, scale, fo, xa, lat, lane);
        const int d = ((y3 & 1) << 1) | (x3 & 1);
        wchild(fdir[d] + (size_t)fo * 1024, xa, lat, xb, lane);
    }
    // ---- L3: children for this jy-half -> x4 (outside aliased region) ----
    {
        const int fo = 21 + n3;
        wlat(f_in, scale, fo, xb, lat, lane);
#pragma unroll
        for (int jx = 0; jx < 2; ++jx)
            wchild(fdir[2 * jy + jx] + (size_t)fo * 1024, xb, lat, &x4[BW * jx], lane);
    }
    // path xa/xb dead from here; region reused for leaf/x5/sy

    // ---- two L4 subtrees ----
    for (int jx = 0; jx < 2; ++jx) {
        const int y4 = 2 * y3 + jy, x4c = 2 * x3 + jx;
        const int fo4 = 85 + y4 * 16 + x4c;
        wlat(f_in, scale, fo4, &x4[BW * jx], lat4, lane);  // L4 latent persists in lat4

        // ---- 2 head-tile-pairs per subtree: p halves; children recomputed per p ----
        for (int p = 0; p < 2; ++p) {
#pragma unroll
            for (int dx2 = 0; dx2 < 2; ++dx2)
                wchild(fdir[2 * p + dx2] + (size_t)fo4 * 1024, &x4[BW * jx], lat4,
                       &x5[BW * dx2], lane);
#pragma unroll
            for (int dx2 = 0; dx2 < 2; ++dx2) {
                const int fo5 = 341 + (2 * y4 + p) * 32 + (2 * x4c + dx2);
                wlat(f_in, scale, fo5, &x5[BW * dx2], lat, lane);
#pragma unroll
                for (int c = 0; c < 4; ++c)
                    wchild_leaf(fdir[c] + (size_t)fo5 * 1024, &x5[BW * dx2], lat,
                                leaf, dx2 * 4 + c, lane);
            }

            // MFMA head: 32 leaf rows (2 tiles of 16) x 48 outs, K=64
            f32x4 acc[2][3];
#pragma unroll
            for (int t = 0; t < 2; ++t)
#pragma unroll
                for (int mt = 0; mt < 3; ++mt)
                    acc[t][mt] = *(const f32x4*)&s_hb[mt * 16 + q * 4];
#pragma unroll
            for (int kc = 0; kc < 2; ++kc)
#pragma unroll
                for (int t = 0; t < 2; ++t) {
                    const short8 bfrag = *(const short8*)&leaf[(t * 16 + n) * 72 + kc * 32 + q * 8];
#pragma unroll
                    for (int mt = 0; mt < 3; ++mt)
                        acc[t][mt] = __builtin_amdgcn_mfma_f32_16x16x32_bf16(afrag[mt][kc], bfrag, acc[t][mt], 0, 0, 0);
                }

            // stage y: [4b][3ch][8r][16px]  (sy aliases leaf/x5 -- both dead now)
#pragma unroll
            for (int t = 0; t < 2; ++t)
#pragma unroll
                for (int mt = 0; mt < 3; ++mt)
#pragma unroll
                    for (int r = 0; r < 4; ++r) {
                        const int u = mt * 4 + r;
                        const int ofs = ((sy_pk[u >> 1] >> (16 * (u & 1))) & 0xffff) + t * 768;
                        sy[ofs] = acc[t][mt][r];
                    }

            // full-line stores: rows of 16 px (64 B); 384 float4 chunks = 6/lane
            const int base_row = (4 * y3 + 2 * jy + p) * 8;
            const int base_col = (4 * x3 + 2 * jx) * 8;
#pragma unroll
            for (int s = 0; s < 6; ++s) {
                const int i  = lane + 64 * s;      // 0..383 float4 chunks
                const int c4 = i & 3;
                const int r2 = (i >> 2) & 7;
                const int bc = i >> 5;             // b*3+ch, 0..11
                const float4 v = *(const float4*)&sy[(bc * 8 + r2) * 16 + c4 * 4];
                const size_t off = ((size_t)((bg * 16 + wv * 4 + bc / 3) * 3 + (bc % 3))) * 65536
                                 + (size_t)(base_row + r2) * 256 + base_col + c4 * 4;
                *(float4*)&out[off] = v;
            }
        } // p
    } // jx
}

extern "C" void kernel_launch(void* const* d_in, const int* in_sizes, int n_in,
                              void* d_out, int out_size, void* d_ws, size_t ws_size,
                              hipStream_t stream) {
    const float* x    = (const float*)d_in[0];
    const float* f_in = (const float*)d_in[1];
    const float* f_tl = (const float*)d_in[2];
    const float* f_tr = (const float*)d_in[3];
    const float* f_bl = (const float*)d_in[4];
    const float* f_br = (const float*)d_in[5];
    const float* sc   = (const float*)d_in[6];
    const float* hw   = (const float*)d_in[7];
    const float* hb   = (const float*)d_in[8];
    float* out = (float*)d_out;

    dim3 grid(64, 8, 2);
    qtree_kernel<<<grid, NTHR, 0, stream>>>(x, f_in, f_tl, f_tr, f_bl, f_br, sc, hw, hb, out);
}